// Round 1
// baseline (727.626 us; speedup 1.0000x reference)
//
#include <hip/hip_runtime.h>

// VoxelToPoint: out[b][n][c] = valid ? vf[b][c][xi][yi][zi] : 0
// vf: (B, C, 64, 64, 64) fp32; coords: (B, N, 3) int32 (x,y,z); out: (B, N, C) fp32
// One wave (64 lanes) per point; lane index = channel. Output writes coalesce
// to one 256 B store per wave; feature reads are the unavoidable 64-line gather.

#define CCH 64
#define DDIM 64
#define HDIM 64
#define WDIM 64
#define DHW (DDIM * HDIM * WDIM)

__global__ __launch_bounds__(256) void VoxelToPoint_kernel(
    const float* __restrict__ vf,
    const int* __restrict__ coords,
    float* __restrict__ out,
    int B, int N) {
  int gid = blockIdx.x * blockDim.x + threadIdx.x;
  int point = gid >> 6;   // one wave per point
  int lane = gid & 63;    // channel
  int total = B * N;
  if (point >= total) return;
  int b = point / N;
  int n = point - b * N;

  const int* cp = coords + ((size_t)b * N + n) * 3;
  int x = cp[0];
  int y = cp[1];
  int z = cp[2];
  // Reference semantics: valid only checks upper bound; clamp for safe gather.
  bool valid = (x < DDIM) && (y < HDIM) && (z < WDIM);
  int xi = min(max(x, 0), DDIM - 1);
  int yi = min(max(y, 0), HDIM - 1);
  int zi = min(max(z, 0), WDIM - 1);
  int idx = (xi * HDIM + yi) * WDIM + zi;

  float val = 0.0f;
  if (valid) {
    val = vf[(size_t)(b * CCH + lane) * DHW + idx];
  }
  out[((size_t)b * N + n) * CCH + lane] = val;
}

extern "C" void kernel_launch(void* const* d_in, const int* in_sizes, int n_in,
                              void* d_out, int out_size, void* d_ws, size_t ws_size,
                              hipStream_t stream) {
  const float* vf = (const float*)d_in[0];
  const int* coords = (const int*)d_in[1];
  // d_in[2] is num_points on device; derive sizes from in_sizes instead.
  float* out = (float*)d_out;

  int B = in_sizes[0] / (CCH * DHW);       // 4
  int N = in_sizes[1] / (B * 3);           // 100000

  int total_threads = B * N * 64;          // one wave per point
  int block = 256;
  int grid = (total_threads + block - 1) / block;
  VoxelToPoint_kernel<<<grid, block, 0, stream>>>(vf, coords, out, B, N);
}

// Round 2
// 582.806 us; speedup vs baseline: 1.2485x; 1.2485x over previous
//
#include <hip/hip_runtime.h>

// VoxelToPoint via counting sort for cache locality.
// Problem: 400k random points each gather 64 channels (stride 1 MiB) from a
// 256 MB fp32 grid. Unsorted, every access is a cold 64B-line miss: 400k*64*64B
// = 1.6 GB fetch (measured R1: 1.515 GB). Each line is shared by ~6.1 points;
// sorting points by line-group makes sharers temporally adjacent -> L2 hits.
//
// Pipeline (all on stream, graph-safe, workspace only):
//  k0 zero     : offsets[65536] = 0
//  k1 hist     : count points per bucket (b*16384 + idx>>4)   [idx>>4 = 64B line group]
//  k2 scan     : exclusive prefix sum (single 1024-thr block)
//  k3 scatter  : records[pos] = (pid, idx|invalid_bit), sorted order
//  k4 gather   : one wave per sorted point; lane = channel; XCD-swizzled blocks
//                so contiguous sorted chunks share one XCD's L2.

#define DDIM 64
#define HDIM 64
#define WDIM 64
#define CCH 64
#define DHW (DDIM * HDIM * WDIM)
#define NBUCKETS_PER_B 16384        // DHW / 16 (16 floats per 64B line)
#define MAXB 8
#define NBUCKETS (MAXB * NBUCKETS_PER_B)

__global__ void zero_kernel(int* __restrict__ counts, int n) {
  int i = blockIdx.x * blockDim.x + threadIdx.x;
  if (i < n) counts[i] = 0;
}

__device__ __forceinline__ void decode_point(const int* cp, bool& valid, int& idx) {
  int x = cp[0], y = cp[1], z = cp[2];
  valid = (x < DDIM) && (y < HDIM) && (z < WDIM);  // reference: upper bound only
  int xi = min(max(x, 0), DDIM - 1);
  int yi = min(max(y, 0), HDIM - 1);
  int zi = min(max(z, 0), WDIM - 1);
  idx = (xi * HDIM + yi) * WDIM + zi;
}

__global__ void hist_kernel(const int* __restrict__ coords, int* __restrict__ counts,
                            int B, int N) {
  int p = blockIdx.x * blockDim.x + threadIdx.x;
  if (p >= B * N) return;
  int b = p / N;
  bool valid; int idx;
  decode_point(coords + (size_t)p * 3, valid, idx);
  int bucket = b * NBUCKETS_PER_B + (idx >> 4);
  atomicAdd(&counts[bucket], 1);
}

// Exclusive scan over NBUCKETS ints, single block of 1024 threads, 2-pass.
__global__ __launch_bounds__(1024) void scan_kernel(int* __restrict__ counts, int nbuckets) {
  __shared__ int sums[1024];
  int t = threadIdx.x;
  int per = nbuckets / 1024;  // 128 with MAXB=8... actually NBUCKETS/1024
  int base = t * per;
  int run = 0;
  for (int i = 0; i < per; i++) run += counts[base + i];
  sums[t] = run;
  __syncthreads();
  // Hillis-Steele inclusive scan over 1024 elements in LDS
  for (int off = 1; off < 1024; off <<= 1) {
    int v = sums[t];
    int add = (t >= off) ? sums[t - off] : 0;
    __syncthreads();
    sums[t] = v + add;
    __syncthreads();
  }
  int excl = (t > 0) ? sums[t - 1] : 0;
  // second pass: rewrite counts as exclusive offsets
  run = excl;
  for (int i = 0; i < per; i++) {
    int c = counts[base + i];
    counts[base + i] = run;
    run += c;
  }
}

__global__ void scatter_kernel(const int* __restrict__ coords, int* __restrict__ offsets,
                               int2* __restrict__ records, int B, int N) {
  int p = blockIdx.x * blockDim.x + threadIdx.x;
  if (p >= B * N) return;
  int b = p / N;
  bool valid; int idx;
  decode_point(coords + (size_t)p * 3, valid, idx);
  int bucket = b * NBUCKETS_PER_B + (idx >> 4);
  int pos = atomicAdd(&offsets[bucket], 1);
  records[pos] = make_int2(p, idx | (valid ? 0 : (1 << 31)));
}

__global__ __launch_bounds__(256) void gather_kernel(const float* __restrict__ vf,
                                                     const int2* __restrict__ records,
                                                     float* __restrict__ out,
                                                     int B, int N, int nb) {
  // XCD swizzle: heuristic XCD = blockIdx % 8; give each XCD a contiguous
  // chunk of the sorted order so same-line points share one L2. nb % 8 == 0.
  int chunk = nb >> 3;
  int lb = (blockIdx.x & 7) * chunk + (blockIdx.x >> 3);
  int s = lb * 4 + (int)(threadIdx.x >> 6);  // sorted position (4 waves/block)
  int lane = threadIdx.x & 63;               // channel
  if (s >= B * N) return;
  int2 r = records[s];
  int pid = r.x;
  int idx = r.y & (DHW - 1);
  bool valid = (r.y >= 0);
  int b = pid / N;
  float v = 0.0f;
  if (valid) v = vf[(size_t)(b * CCH + lane) * DHW + idx];
  out[(size_t)pid * CCH + lane] = v;
}

// Fallback (R1 kernel) if workspace is too small.
__global__ __launch_bounds__(256) void direct_kernel(const float* __restrict__ vf,
                                                     const int* __restrict__ coords,
                                                     float* __restrict__ out,
                                                     int B, int N) {
  int gid = blockIdx.x * blockDim.x + threadIdx.x;
  int point = gid >> 6;
  int lane = gid & 63;
  if (point >= B * N) return;
  int b = point / N;
  bool valid; int idx;
  decode_point(coords + (size_t)point * 3, valid, idx);
  float v = 0.0f;
  if (valid) v = vf[(size_t)(b * CCH + lane) * DHW + idx];
  out[(size_t)point * CCH + lane] = v;
}

extern "C" void kernel_launch(void* const* d_in, const int* in_sizes, int n_in,
                              void* d_out, int out_size, void* d_ws, size_t ws_size,
                              hipStream_t stream) {
  const float* vf = (const float*)d_in[0];
  const int* coords = (const int*)d_in[1];
  float* out = (float*)d_out;

  int B = in_sizes[0] / (CCH * DHW);  // 4
  int N = in_sizes[1] / (B * 3);      // 100000
  int total = B * N;

  int nbuckets = B * NBUCKETS_PER_B;  // 65536 for B=4
  size_t off_bytes = (size_t)nbuckets * sizeof(int);
  off_bytes = (off_bytes + 255) & ~(size_t)255;  // align records
  size_t need = off_bytes + (size_t)total * sizeof(int2);

  if (ws_size < need || (nbuckets % 1024) != 0) {
    int threads = total * 64;
    direct_kernel<<<(threads + 255) / 256, 256, 0, stream>>>(vf, coords, out, B, N);
    return;
  }

  int* offsets = (int*)d_ws;
  int2* records = (int2*)((char*)d_ws + off_bytes);

  zero_kernel<<<(nbuckets + 255) / 256, 256, 0, stream>>>(offsets, nbuckets);
  hist_kernel<<<(total + 255) / 256, 256, 0, stream>>>(coords, offsets, B, N);
  scan_kernel<<<1, 1024, 0, stream>>>(offsets, nbuckets);
  scatter_kernel<<<(total + 255) / 256, 256, 0, stream>>>(coords, offsets, records, B, N);

  int nb = (total + 3) / 4;        // 4 points (waves) per 256-thr block
  nb = (nb + 7) & ~7;              // multiple of 8 for the XCD swizzle
  gather_kernel<<<nb, 256, 0, stream>>>(vf, records, out, B, N, nb);
}

// Round 3
// 555.041 us; speedup vs baseline: 1.3109x; 1.0500x over previous
//
#include <hip/hip_runtime.h>

// VoxelToPoint via counting sort + per-line-group LDS gather.
// R2 post-mortem: sorted gather was address-divergence-bound (64 distinct
// 64B lines per wave-load, 25.6M line-requests). R3: one workgroup per
// line-group loads its 16 voxels x 64 channels (4KB) into LDS ONCE with
// float4 (4 lanes/line), then the ~6 points sharing the group read LDS and
// write coalesced 256B. Each feature line is requested exactly once.
//
// Pipeline: zero -> hist -> scan -> scatter(4B records) -> gather2.

#define DDIM 64
#define HDIM 64
#define WDIM 64
#define CCH 64
#define DHW (DDIM * HDIM * WDIM)          // 1<<18
#define GROUPS_PER_B 16384                 // DHW/16: one 64B line-group per 16 z-voxels
#define LDS_STRIDE 17                      // 16 + 1 pad: odd stride -> 2-way bank alias (free)

__global__ void zero_kernel(int* __restrict__ counts, int n) {
  int i = blockIdx.x * blockDim.x + threadIdx.x;
  if (i < n) counts[i] = 0;
}

__device__ __forceinline__ void decode_point(const int* cp, bool& valid, int& idx) {
  int x = cp[0], y = cp[1], z = cp[2];
  valid = (x < DDIM) && (y < HDIM) && (z < WDIM);  // reference: upper bound only
  int xi = min(max(x, 0), DDIM - 1);
  int yi = min(max(y, 0), HDIM - 1);
  int zi = min(max(z, 0), WDIM - 1);
  idx = (xi * HDIM + yi) * WDIM + zi;
}

__global__ void hist_kernel(const int* __restrict__ coords, int* __restrict__ counts,
                            int B, int N) {
  int p = blockIdx.x * blockDim.x + threadIdx.x;
  if (p >= B * N) return;
  int b = p / N;
  bool valid; int idx;
  decode_point(coords + (size_t)p * 3, valid, idx);
  atomicAdd(&counts[b * GROUPS_PER_B + (idx >> 4)], 1);
}

// Exclusive scan over nbuckets ints, single 1024-thread block, 2-pass.
__global__ __launch_bounds__(1024) void scan_kernel(int* __restrict__ counts, int nbuckets) {
  __shared__ int sums[1024];
  int t = threadIdx.x;
  int per = nbuckets / 1024;
  int base = t * per;
  int run = 0;
  for (int i = 0; i < per; i++) run += counts[base + i];
  sums[t] = run;
  __syncthreads();
  for (int off = 1; off < 1024; off <<= 1) {
    int v = sums[t];
    int add = (t >= off) ? sums[t - off] : 0;
    __syncthreads();
    sums[t] = v + add;
    __syncthreads();
  }
  run = (t > 0) ? sums[t - 1] : 0;
  for (int i = 0; i < per; i++) {
    int c = counts[base + i];
    counts[base + i] = run;
    run += c;
  }
}

// records[pos] = pid | zoff<<19 | invalid<<23   (pid < 2^19, zoff = idx&15)
__global__ void scatter_kernel(const int* __restrict__ coords, int* __restrict__ offsets,
                               int* __restrict__ records, int B, int N) {
  int p = blockIdx.x * blockDim.x + threadIdx.x;
  if (p >= B * N) return;
  int b = p / N;
  bool valid; int idx;
  decode_point(coords + (size_t)p * 3, valid, idx);
  int pos = atomicAdd(&offsets[b * GROUPS_PER_B + (idx >> 4)], 1);
  records[pos] = p | ((idx & 15) << 19) | (valid ? 0 : (1 << 23));
}

// One workgroup per (b, line-group). After scatter, offsets[g] = inclusive end
// of group g; start = offsets[g-1] (groups are contiguous).
__global__ __launch_bounds__(256) void gather2_kernel(
    const float* __restrict__ vf, const int* __restrict__ offsets,
    const int* __restrict__ records, float* __restrict__ out) {
  __shared__ float lds[CCH * LDS_STRIDE];
  int g = blockIdx.x;
  int start = (g == 0) ? 0 : offsets[g - 1];
  int end = offsets[g];
  if (start == end) return;  // uniform: whole block exits before barrier
  int b = g >> 14;           // GROUPS_PER_B = 1<<14
  int group = g & (GROUPS_PER_B - 1);
  int t = threadIdx.x;

  // Stage 4KB: 64 channels x 16 floats. ch = t>>2, 16B chunk = t&3.
  {
    int ch = t >> 2;
    int sub = t & 3;
    const float* src = vf + ((size_t)(b * CCH + ch) << 18) + (group << 4) + (sub << 2);
    float4 v4 = *(const float4*)src;
    float* dst = &lds[ch * LDS_STRIDE + (sub << 2)];
    dst[0] = v4.x; dst[1] = v4.y; dst[2] = v4.z; dst[3] = v4.w;
  }
  __syncthreads();

  int ch = t & 63;
  for (int s = start + (t >> 6); s < end; s += 4) {
    int r = records[s];              // 64 lanes same addr -> broadcast
    int pid = r & 0x7FFFF;
    int zoff = (r >> 19) & 15;
    float v = (r & (1 << 23)) ? 0.0f : lds[ch * LDS_STRIDE + zoff];
    out[((size_t)pid << 6) + ch] = v;  // 256B coalesced per point
  }
}

// Fallback if workspace too small.
__global__ __launch_bounds__(256) void direct_kernel(const float* __restrict__ vf,
                                                     const int* __restrict__ coords,
                                                     float* __restrict__ out,
                                                     int B, int N) {
  int gid = blockIdx.x * blockDim.x + threadIdx.x;
  int point = gid >> 6;
  int lane = gid & 63;
  if (point >= B * N) return;
  int b = point / N;
  bool valid; int idx;
  decode_point(coords + (size_t)point * 3, valid, idx);
  float v = 0.0f;
  if (valid) v = vf[(size_t)(b * CCH + lane) * DHW + idx];
  out[(size_t)point * CCH + lane] = v;
}

extern "C" void kernel_launch(void* const* d_in, const int* in_sizes, int n_in,
                              void* d_out, int out_size, void* d_ws, size_t ws_size,
                              hipStream_t stream) {
  const float* vf = (const float*)d_in[0];
  const int* coords = (const int*)d_in[1];
  float* out = (float*)d_out;

  int B = in_sizes[0] / (CCH * DHW);  // 4
  int N = in_sizes[1] / (B * 3);      // 100000
  int total = B * N;

  int nbuckets = B * GROUPS_PER_B;    // 65536
  size_t off_bytes = ((size_t)nbuckets * sizeof(int) + 255) & ~(size_t)255;
  size_t need = off_bytes + (size_t)total * sizeof(int);

  if (ws_size < need || (nbuckets % 1024) != 0 || total >= (1 << 19)) {
    int threads = total * 64;
    direct_kernel<<<(threads + 255) / 256, 256, 0, stream>>>(vf, coords, out, B, N);
    return;
  }

  int* offsets = (int*)d_ws;
  int* records = (int*)((char*)d_ws + off_bytes);

  zero_kernel<<<(nbuckets + 255) / 256, 256, 0, stream>>>(offsets, nbuckets);
  hist_kernel<<<(total + 255) / 256, 256, 0, stream>>>(coords, offsets, B, N);
  scan_kernel<<<1, 1024, 0, stream>>>(offsets, nbuckets);
  scatter_kernel<<<(total + 255) / 256, 256, 0, stream>>>(coords, offsets, records, B, N);
  gather2_kernel<<<nbuckets, 256, 0, stream>>>(vf, offsets, records, out);
}